// Round 7
// baseline (348.366 us; speedup 1.0000x reference)
//
#include <hip/hip_runtime.h>
#include <hip/hip_bf16.h>

typedef unsigned short u16;
typedef unsigned int u32;
typedef __attribute__((ext_vector_type(8))) __bf16 bhalf8;   // 16x16x32 A/B operand (4 VGPRs)
typedef __attribute__((ext_vector_type(8))) u16 us8;         // 16B vector
typedef __attribute__((ext_vector_type(4))) u16 us4;         // 8B vector
typedef __attribute__((ext_vector_type(4))) float f32x4;     // MFMA C/D operand

#if __has_builtin(__builtin_amdgcn_mfma_f32_16x16x16_bf16)
typedef __attribute__((ext_vector_type(4))) __bf16 bhalf4;   // 16x16x16 A/B operand (2 VGPRs)
#define MFMA16(a, b, c) __builtin_amdgcn_mfma_f32_16x16x16_bf16(a, b, c, 0, 0, 0)
#else
typedef __attribute__((ext_vector_type(4))) short bhalf4;    // bf16 bits in i16 (gfx90a-style)
#define MFMA16(a, b, c) __builtin_amdgcn_mfma_f32_16x16x16bf16_1k(a, b, c, 0, 0, 0)
#endif

#if __has_builtin(__builtin_amdgcn_exp2f)
#define EXP2(x) __builtin_amdgcn_exp2f(x)
#else
#define EXP2(x) exp2f(x)
#endif

__device__ __forceinline__ u16 bf16rne(float f) {
  u32 u = __float_as_uint(f);
  u += 0x7FFFu + ((u >> 16) & 1u);
  return (u16)(u >> 16);
}

__device__ __forceinline__ u32 pkbf(float a, float b) {  // two f32 -> packed bf16x2 (RNE)
  union { __hip_bfloat162 h; u32 w; } u;
  u.h = __float22bfloat162_rn(make_float2(a, b));
  return u.w;
}

// ---------------- fused prep: cast x + transpose-cast both weights ----------------
// blocks [0,8192): cast x fp32->bf16 (4 elems/thread)
// blocks [8192,11264): w_qkv [1024][3072] -> wqkvT [3072][1024] bf16
// blocks [11264,12288): w_out [1024][1024] -> woutT [1024][1024] bf16
__device__ __forceinline__ void tcast_tile(const float* __restrict__ in, u16* __restrict__ out,
                                           int R, int Cn, int c0, int r0, int tid) {
  __shared__ float tile[32][33];
  int tx = tid & 31, ty = tid >> 5;  // 32 x 8
#pragma unroll
  for (int j = 0; j < 4; ++j)
    tile[ty + j * 8][tx] = in[(size_t)(r0 + ty + j * 8) * Cn + c0 + tx];
  __syncthreads();
#pragma unroll
  for (int j = 0; j < 4; ++j)
    out[(size_t)(c0 + ty + j * 8) * R + r0 + tx] = bf16rne(tile[tx][ty + j * 8]);
}

__global__ __launch_bounds__(256) void prep_kernel(const float* __restrict__ x,
                                                   const float* __restrict__ wqkv,
                                                   const float* __restrict__ wout,
                                                   u16* __restrict__ xb,
                                                   u16* __restrict__ wqkvT,
                                                   u16* __restrict__ woutT) {
  int bid = blockIdx.x, tid = threadIdx.x;
  if (bid < 8192) {
    int i = (bid * 256 + tid) * 4;
    float4 f = *(const float4*)(x + i);
    *(uint2*)(xb + i) = make_uint2(pkbf(f.x, f.y), pkbf(f.z, f.w));
  } else if (bid < 11264) {
    int t = bid - 8192;                       // 0..3071  (96 x 32 tiles)
    tcast_tile(wqkv, wqkvT, 1024, 3072, (t % 96) * 32, (t / 96) * 32, tid);
  } else {
    int t = bid - 11264;                      // 0..1023  (32 x 32 tiles)
    tcast_tile(wout, woutT, 1024, 1024, (t % 32) * 32, (t / 32) * 32, tid);
  }
}

// ---------------- bf16 MFMA GEMM: C[M,N] = A[M,K] @ Bt[N,K]^T ----------------
// (unchanged from round 6 — 805 TF, near the m97 structural plateau)
template <int MODE>
__global__ __launch_bounds__(256, 2) void gemm_bt_kernel(
    const u16* __restrict__ A, const u16* __restrict__ Bt, const float* __restrict__ bias,
    float* __restrict__ outf, u16* __restrict__ qb, u16* __restrict__ kb, u16* __restrict__ vb,
    int Mdim, int Ndim, int Kdim) {
  __shared__ __align__(16) u16 lA[128 * 64];
  __shared__ __align__(16) u16 lB[128 * 64];
  const int tid = threadIdx.x;
  const int lane = tid & 63;
  const int col = lane & 15, quad = lane >> 4;
  const int wid = tid >> 6;
  const int gx = (MODE == 0) ? 24 : 8;
  int id = blockIdx.y * gx + blockIdx.x;
  int g = id & 7, j = id >> 3;
  int vy = g * 8 + j / gx;
  int vx = j % gx;
  const int m0 = vy * 128, n0 = vx * 128;
  const int wm = (wid >> 1) * 64, wn = (wid & 1) * 64;
  const float QSC = 0.18033688011112042f;     // log2(e)/sqrt(64), folded into Q

  f32x4 acc[4][4];
#pragma unroll
  for (int i = 0; i < 4; ++i)
#pragma unroll
    for (int j2 = 0; j2 < 4; ++j2) acc[i][j2] = f32x4{0.f, 0.f, 0.f, 0.f};

  for (int k0 = 0; k0 < Kdim; k0 += 64) {
    const u16* Ag = A + (size_t)m0 * Kdim + k0;
    const u16* Bg = Bt + (size_t)n0 * Kdim + k0;
#pragma unroll
    for (int r = 0; r < 4; ++r) {
      int c = r * 256 + tid;
      int row = c >> 3;
      int bblk = (c & 7) ^ (row & 7);
      size_t ldsoff = (size_t)(r * 256 + (tid & 0xC0)) * 8;
      __builtin_amdgcn_global_load_lds(
          (const __attribute__((address_space(1))) void*)(Ag + (size_t)row * Kdim + bblk * 8),
          (__attribute__((address_space(3))) void*)(lA + ldsoff), 16, 0, 0);
      __builtin_amdgcn_global_load_lds(
          (const __attribute__((address_space(1))) void*)(Bg + (size_t)row * Kdim + bblk * 8),
          (__attribute__((address_space(3))) void*)(lB + ldsoff), 16, 0, 0);
    }
    __syncthreads();
#pragma unroll
    for (int ks = 0; ks < 2; ++ks) {
      bhalf8 af[4], bfr[4];
#pragma unroll
      for (int i = 0; i < 4; ++i) {
        int ra = wm + i * 16 + col;
        int rb = wn + i * 16 + col;
        af[i]  = *(const bhalf8*)&lA[ra * 64 + (((ks * 4 + quad) ^ (ra & 7)) * 8)];
        bfr[i] = *(const bhalf8*)&lB[rb * 64 + (((ks * 4 + quad) ^ (rb & 7)) * 8)];
      }
#pragma unroll
      for (int mt = 0; mt < 4; ++mt)
#pragma unroll
        for (int nt = 0; nt < 4; ++nt)
          acc[mt][nt] = __builtin_amdgcn_mfma_f32_16x16x32_bf16(af[mt], bfr[nt], acc[mt][nt], 0, 0, 0);
    }
    __syncthreads();
  }

  if (MODE == 0) {
#pragma unroll
    for (int nt = 0; nt < 4; ++nt) {
      int n = n0 + wn + nt * 16 + col;
      float bv = bias[n];
      int which = n >> 10, cc = n & 1023, hh = cc >> 6, dd = cc & 63;
      if (which == 2) {
#pragma unroll
        for (int mt = 0; mt < 4; ++mt) {
          int t0 = m0 + wm + mt * 16 + quad * 4;
          int bb = t0 >> 11, tt = t0 & 2047;
          us4 w;
#pragma unroll
          for (int reg = 0; reg < 4; ++reg) w[reg] = bf16rne(acc[mt][nt][reg] + bv);
          *(us4*)(vb + ((size_t)(bb * 16 + hh) * 64 + dd) * 2048 + tt) = w;
        }
      } else {
        u16* dst = which ? kb : qb;
        float sc = which ? 1.0f : QSC;
#pragma unroll
        for (int mt = 0; mt < 4; ++mt)
#pragma unroll
          for (int reg = 0; reg < 4; ++reg) {
            int m = m0 + wm + mt * 16 + quad * 4 + reg;
            int bb = m >> 11, tt = m & 2047;
            dst[((size_t)(bb * 16 + hh) * 2048 + tt) * 64 + dd] = bf16rne((acc[mt][nt][reg] + bv) * sc);
          }
      }
    }
  } else {
#pragma unroll
    for (int mt = 0; mt < 4; ++mt)
#pragma unroll
      for (int nt = 0; nt < 4; ++nt) {
        int n = n0 + wn + nt * 16 + col;
        float bv = bias[n];
#pragma unroll
        for (int reg = 0; reg < 4; ++reg) {
          int m = m0 + wm + mt * 16 + quad * 4 + reg;
          outf[(size_t)m * Ndim + n] = acc[mt][nt][reg] + bv;
        }
      }
  }
}

// ---------------- causal flash attention, 64-row k-tiles, 4 blocks/CU ----------------
// 4 waves x 32 q-rows = 128-q-row tiles (qt 0..15), 64-row K/V tiles double-
// buffered (32 KB LDS). Barrier cadence identical to the validated round-4/6
// structure: per tile { barrier; stage(next -> other buf); compute(cur buf) }.
// Hot loop is branch/mask-free (diagonal handled in a 2-tile tail, buffer
// parity compile-time). Per-lane LDS offsets precomputed once: every ds_read
// is base + imm. Fixed-base softmax (Q pre-scaled); P feeds PV MFMA16 from
// registers. XCD swizzle: all 8 blocks of one bh on one XCD.
__global__ __launch_bounds__(256, 4) void attn_kernel(const u16* __restrict__ Q,
                                                      const u16* __restrict__ K,
                                                      const u16* __restrict__ VT,
                                                      u16* __restrict__ aout) {
  __shared__ __align__(16) u16 lK[2][64 * 64];   // 8 KB each
  __shared__ __align__(16) u16 lV[2][64 * 64];   // 8 KB each
  const int tid = threadIdx.x;
  const int lane = tid & 63, wid = tid >> 6;
  const int col = lane & 15, quad = lane >> 4;
  int id = blockIdx.y * 8 + blockIdx.x;
  int g = id & 7, j = id >> 3;                   // j 0..63
  const int bh = g * 8 + (j >> 3);               // 0..63
  const int bx = j & 7;                          // 0..7
  const int b = bh >> 4, h = bh & 15;
  const u16* Qb = Q + (size_t)bh * 2048 * 64;
  const u16* Kb = K + (size_t)bh * 2048 * 64;
  const u16* Vb = VT + (size_t)bh * 64 * 2048;   // [D][T]
  const int wuni = tid & 0xC0;

  // per-lane LDS element offsets (loop-invariant; reads become base + imm)
  const int loffK0 = col * 64 + ((quad ^ (col & 7)) * 8);
  const int loffK1 = col * 64 + (((4 + quad) ^ (col & 7)) * 8);
  int loffV[4];
#pragma unroll
  for (int ntk = 0; ntk < 4; ++ntk)
    loffV[ntk] = col * 64 + (((ntk * 2 + (quad >> 1)) ^ (col & 7)) * 8) + (quad & 1) * 4;

  for (int phase = 0; phase < 2; ++phase) {
    const int qt = (phase == 0) ? (15 - bx) : bx;

    // ---- stage 64-row k-tile kt into buffer bufi (async, 16B chunks) ----
    auto stage = [&](int kt, int bufi) {
      const u16* Kg = Kb + (size_t)kt * 64 * 64;
      const u16* Vg = Vb + (size_t)kt * 64;
#pragma unroll
      for (int r = 0; r < 2; ++r) {
        int c = r * 256 + tid;            // chunk 0..511
        size_t ldsoff = (size_t)(r * 256 + wuni) * 8;
        int row = c >> 3, blk = (c & 7) ^ (row & 7);
        __builtin_amdgcn_global_load_lds(
            (const __attribute__((address_space(1))) void*)(Kg + (size_t)row * 64 + blk * 8),
            (__attribute__((address_space(3))) void*)(&lK[bufi][0] + ldsoff), 16, 0, 0);
        __builtin_amdgcn_global_load_lds(
            (const __attribute__((address_space(1))) void*)(Vg + (size_t)row * 2048 + blk * 8),
            (__attribute__((address_space(3))) void*)(&lV[bufi][0] + ldsoff), 16, 0, 0);
      }
    };

    // Q fragments (loop-invariant; Q carries the softmax scale)
    bhalf8 qf[2][2];
#pragma unroll
    for (int ntq = 0; ntq < 2; ++ntq)
#pragma unroll
      for (int ks = 0; ks < 2; ++ks)
        qf[ntq][ks] = *(const bhalf8*)(Qb + (size_t)(qt * 128 + wid * 32 + ntq * 16 + col) * 64 +
                                       ks * 32 + quad * 8);

    f32x4 oacc[4][2];   // O^T: row d = dt*16+quad*4+reg, col q
    float lr[2] = {0.f, 0.f};
#pragma unroll
    for (int dt = 0; dt < 4; ++dt)
#pragma unroll
      for (int ntq = 0; ntq < 2; ++ntq) oacc[dt][ntq] = f32x4{0.f, 0.f, 0.f, 0.f};

    // full 64-row tile: no masks, ntk 0..3
    auto compute_full = [&](const u16* Kbuf, const u16* Vbuf) {
      f32x4 sacc[4][2];
#pragma unroll
      for (int ntk = 0; ntk < 4; ++ntk)
#pragma unroll
        for (int ntq = 0; ntq < 2; ++ntq) sacc[ntk][ntq] = f32x4{0.f, 0.f, 0.f, 0.f};
#pragma unroll
      for (int ks = 0; ks < 2; ++ks) {
        const int lk = ks ? loffK1 : loffK0;
        bhalf8 kf[4];
#pragma unroll
        for (int ntk = 0; ntk < 4; ++ntk) kf[ntk] = *(const bhalf8*)(Kbuf + lk + ntk * 1024);
#pragma unroll
        for (int ntk = 0; ntk < 4; ++ntk)
#pragma unroll
          for (int ntq = 0; ntq < 2; ++ntq)
            sacc[ntk][ntq] = __builtin_amdgcn_mfma_f32_16x16x32_bf16(kf[ntk], qf[ntq][ks],
                                                                     sacc[ntk][ntq], 0, 0, 0);
      }
#pragma unroll
      for (int ntk = 0; ntk < 4; ++ntk) {
        bhalf4 vf[4];
#pragma unroll
        for (int dt = 0; dt < 4; ++dt)
          vf[dt] = *(const bhalf4*)(Vbuf + loffV[ntk] + dt * 1024);
#pragma unroll
        for (int ntq = 0; ntq < 2; ++ntq) {
          float p0 = EXP2(sacc[ntk][ntq][0]);
          float p1 = EXP2(sacc[ntk][ntq][1]);
          float p2 = EXP2(sacc[ntk][ntq][2]);
          float p3 = EXP2(sacc[ntk][ntq][3]);
          lr[ntq] += (p0 + p1) + (p2 + p3);
          union { u32 w[2]; bhalf4 v; } pfu;
          pfu.w[0] = pkbf(p0, p1);
          pfu.w[1] = pkbf(p2, p3);
#pragma unroll
          for (int dt = 0; dt < 4; ++dt)
            oacc[dt][ntq] = MFMA16(vf[dt], pfu.v, oacc[dt][ntq]);
        }
      }
    };

    // diagonal 64-row tile: wave processes ntk < ntkhi, masks its 2 partial sub-tiles
    auto compute_diag = [&](const u16* Kbuf, const u16* Vbuf, int kbase) {
      const int ntkhi = (wid & 1) ? 4 : 2;
      const int ntklo = (wid & 1) * 2;
      f32x4 sacc[4][2];
#pragma unroll
      for (int ntk = 0; ntk < 4; ++ntk)
#pragma unroll
        for (int ntq = 0; ntq < 2; ++ntq) sacc[ntk][ntq] = f32x4{0.f, 0.f, 0.f, 0.f};
#pragma unroll
      for (int ks = 0; ks < 2; ++ks) {
        const int lk = ks ? loffK1 : loffK0;
        bhalf8 kf[4];
#pragma unroll
        for (int ntk = 0; ntk < 4; ++ntk)
          if (ntk < ntkhi) kf[ntk] = *(const bhalf8*)(Kbuf + lk + ntk * 1024);
#pragma unroll
        for (int ntk = 0; ntk < 4; ++ntk)
          if (ntk < ntkhi)
#pragma unroll
            for (int ntq = 0; ntq < 2; ++ntq)
              sacc[ntk][ntq] = __builtin_amdgcn_mfma_f32_16x16x32_bf16(kf[ntk], qf[ntq][ks],
                                                                       sacc[ntk][ntq], 0, 0, 0);
      }
#pragma unroll
      for (int ntk = 0; ntk < 4; ++ntk)
        if (ntk >= ntklo && ntk < ntkhi)
#pragma unroll
          for (int ntq = 0; ntq < 2; ++ntq) {
            int qloc = wid * 32 + ntq * 16 + col;
#pragma unroll
            for (int reg = 0; reg < 4; ++reg) {
              int kloc = kbase + ntk * 16 + quad * 4 + reg;
              if (kloc > qloc) sacc[ntk][ntq][reg] = -1e30f;
            }
          }
#pragma unroll
      for (int ntk = 0; ntk < 4; ++ntk)
        if (ntk < ntkhi) {
          bhalf4 vf[4];
#pragma unroll
          for (int dt = 0; dt < 4; ++dt)
            vf[dt] = *(const bhalf4*)(Vbuf + loffV[ntk] + dt * 1024);
#pragma unroll
          for (int ntq = 0; ntq < 2; ++ntq) {
            float p0 = EXP2(sacc[ntk][ntq][0]);
            float p1 = EXP2(sacc[ntk][ntq][1]);
            float p2 = EXP2(sacc[ntk][ntq][2]);
            float p3 = EXP2(sacc[ntk][ntq][3]);
            lr[ntq] += (p0 + p1) + (p2 + p3);
            union { u32 w[2]; bhalf4 v; } pfu;
            pfu.w[0] = pkbf(p0, p1);
            pfu.w[1] = pkbf(p2, p3);
#pragma unroll
            for (int dt = 0; dt < 4; ++dt)
              oacc[dt][ntq] = MFMA16(vf[dt], pfu.v, oacc[dt][ntq]);
          }
        }
    };

    stage(0, 0);
    for (int p = 0; p < qt; ++p) {
      // tile 2p (buf 0)
      __syncthreads();                 // drains stage(2p); all waves done reading buf0
      stage(2 * p + 1, 1);
      compute_full(&lK[0][0], &lV[0][0]);
      // tile 2p+1 (buf 1)
      __syncthreads();
      stage(2 * p + 2, 0);
      compute_full(&lK[1][0], &lV[1][0]);
    }
    // diag-A: tile 2qt (buf 0). waves 2,3 fully unmasked; waves 0,1 partial.
    __syncthreads();
    stage(2 * qt + 1, 1);
    if (wid >= 2) compute_full(&lK[0][0], &lV[0][0]);
    else          compute_diag(&lK[0][0], &lV[0][0], 0);
    // diag-B: tile 2qt+1 (buf 1). only waves 2,3 have unmasked rows.
    __syncthreads();
    if (wid >= 2) compute_diag(&lK[1][0], &lV[1][0], 64);

    // epilogue: reduce l across quads, normalize, packed stores (d contiguous)
#pragma unroll
    for (int ntq = 0; ntq < 2; ++ntq) {
      float r = lr[ntq];
      r += __shfl_xor(r, 16);
      r += __shfl_xor(r, 32);
      float inv = 1.f / r;
      int q = qt * 128 + wid * 32 + ntq * 16 + col;
      size_t base = ((size_t)(b * 2048 + q)) * 1024 + h * 64;
#pragma unroll
      for (int dt = 0; dt < 4; ++dt) {
        us4 w;
#pragma unroll
        for (int reg = 0; reg < 4; ++reg) w[reg] = bf16rne(oacc[dt][ntq][reg] * inv);
        *(us4*)(aout + base + dt * 16 + quad * 4) = w;
      }
    }
    __syncthreads();  // protect LDS buffers before next phase's stage(0,0)
  }
}

// ---------------- launch ----------------
// Workspace layout (bytes), total ~92.3 MB:
//  xb    @ 0         : 8192x1024 bf16      (16777216)
//  wqkvT @ 16777216  : 3072x1024 bf16      ( 6291456)
//  woutT @ 23068672  : 1024x1024 bf16      ( 2097152)
//  q     @ 25165824  : [B,H,T,D] bf16 (pre-scaled by log2e/8)  (16777216)
//  k     @ 41943040  : [B,H,T,D] bf16      (16777216)
//  vT    @ 58720256  : [B,H,D,T] bf16      (16777216)
//  aout  @ 75497472  : 8192x1024 bf16      (16777216)
extern "C" void kernel_launch(void* const* d_in, const int* in_sizes, int n_in,
                              void* d_out, int out_size, void* d_ws, size_t ws_size,
                              hipStream_t stream) {
  const float* x     = (const float*)d_in[0];
  const float* w_qkv = (const float*)d_in[1];
  const float* b_qkv = (const float*)d_in[2];
  const float* w_out = (const float*)d_in[3];
  const float* b_out = (const float*)d_in[4];
  float* out = (float*)d_out;
  char* ws = (char*)d_ws;
  u16* xb    = (u16*)(ws);
  u16* wqkvT = (u16*)(ws + 16777216);
  u16* woutT = (u16*)(ws + 23068672);
  u16* qb    = (u16*)(ws + 25165824);
  u16* kb    = (u16*)(ws + 41943040);
  u16* vT    = (u16*)(ws + 58720256);
  u16* ab    = (u16*)(ws + 75497472);

  prep_kernel<<<12288, 256, 0, stream>>>(x, w_qkv, w_out, xb, wqkvT, woutT);
  gemm_bt_kernel<0><<<dim3(24, 64), 256, 0, stream>>>(xb, wqkvT, b_qkv, nullptr, qb, kb, vT,
                                                      8192, 3072, 1024);
  attn_kernel<<<dim3(8, 64), 256, 0, stream>>>(qb, kb, vT, ab);
  gemm_bt_kernel<1><<<dim3(8, 64), 256, 0, stream>>>(ab, woutT, b_out, out, nullptr, nullptr,
                                                     nullptr, 8192, 1024, 1024);
}